// Round 5
// baseline (598.984 us; speedup 1.0000x reference)
//
#include <hip/hip_runtime.h>
#include <hip/hip_bf16.h>

typedef __hip_bfloat16 bf16;

// exact bf16<->f32 conversion helpers (bf16 = top 16 bits of f32, RNE round)
__device__ __forceinline__ float us2f(unsigned short u) {
  union { unsigned int ui; float f; } cv; cv.ui = ((unsigned int)u) << 16; return cv.f;
}
__device__ __forceinline__ unsigned short f2us(float f) {
  union { float f; unsigned int u; } cv; cv.f = f;
  unsigned int u = cv.u;
  return (unsigned short)((u + 0x7fffu + ((u >> 16) & 1u)) >> 16);
}

#define WEXP 0.36787944117144233f  // exp(-1)

// f_out[n][64] = relu(in[n][KDIM] @ W[KDIM][64] + b); in fp32 row-stride in_stride.
// fout: bf16 [n][64]. If xcopy != nullptr, copies the fp32 input rows to
// xcopy + row*320 (x pass-through; only used with KDIM=64).
// Block: 256 threads = 16 col-groups(x4 cols) x 16 row-pairs -> 32 rows/block.
template<int KDIM>
__global__ __launch_bounds__(256) void dense_relu_kernel(
    const float* __restrict__ in, int in_stride,
    const float* __restrict__ W, const float* __restrict__ b,
    bf16* __restrict__ fout, float* __restrict__ xcopy, int n)
{
  __shared__ float Ws[KDIM][68];       // pad 64->68: keeps 16B row alignment, breaks conflicts
  __shared__ float Xs[32][KDIM + 1];   // +1 pad breaks same-bank across rows
  const int tx = threadIdx.x;
  const int row0 = blockIdx.x * 32;

  // stage W (KDIM x 64 fp32), float4 vector loads
  for (int t = tx; t < KDIM * 16; t += 256) {
    float4 w4 = ((const float4*)W)[t];
    int k = t >> 4, c4 = (t & 15) * 4;
    Ws[k][c4 + 0] = w4.x; Ws[k][c4 + 1] = w4.y; Ws[k][c4 + 2] = w4.z; Ws[k][c4 + 3] = w4.w;
  }

  // stage X rows (32 x KDIM fp32)
  constexpr int CH = KDIM / 4;  // float4 chunks per row
  for (int t = tx; t < 32 * CH; t += 256) {
    int rr = t / CH, kc = t - rr * CH;
    int row = row0 + rr;
    float4 f4 = make_float4(0.f, 0.f, 0.f, 0.f);
    if (row < n)
      f4 = *(const float4*)(in + (size_t)row * in_stride + kc * 4);
    Xs[rr][kc * 4 + 0] = f4.x; Xs[rr][kc * 4 + 1] = f4.y;
    Xs[rr][kc * 4 + 2] = f4.z; Xs[rr][kc * 4 + 3] = f4.w;
    if (xcopy != nullptr && row < n)
      *(float4*)(xcopy + (size_t)row * 320 + kc * 4) = f4;
  }
  __syncthreads();

  const int c = tx & 15;        // col group: cols 4c..4c+3
  const int r = tx >> 4;        // row pair: rows 2r, 2r+1
  float acc0[4] = {0.f, 0.f, 0.f, 0.f};
  float acc1[4] = {0.f, 0.f, 0.f, 0.f};
#pragma unroll 8
  for (int k = 0; k < KDIM; ++k) {
    const float4 w4 = *(const float4*)&Ws[k][c * 4];
    const float x0 = Xs[2 * r][k];
    const float x1 = Xs[2 * r + 1][k];
    acc0[0] += x0 * w4.x; acc0[1] += x0 * w4.y; acc0[2] += x0 * w4.z; acc0[3] += x0 * w4.w;
    acc1[0] += x1 * w4.x; acc1[1] += x1 * w4.y; acc1[2] += x1 * w4.z; acc1[3] += x1 * w4.w;
  }

  const float4 bb = *(const float4*)&b[c * 4];

  int row = row0 + 2 * r;
  if (row < n) {
    ushort4 o;
    o.x = f2us(fmaxf(acc0[0] + bb.x, 0.f));
    o.y = f2us(fmaxf(acc0[1] + bb.y, 0.f));
    o.z = f2us(fmaxf(acc0[2] + bb.z, 0.f));
    o.w = f2us(fmaxf(acc0[3] + bb.w, 0.f));
    *(ushort4*)((unsigned short*)fout + (size_t)row * 64 + c * 4) = o;
  }
  row = row0 + 2 * r + 1;
  if (row < n) {
    ushort4 o;
    o.x = f2us(fmaxf(acc1[0] + bb.x, 0.f));
    o.y = f2us(fmaxf(acc1[1] + bb.y, 0.f));
    o.z = f2us(fmaxf(acc1[2] + bb.z, 0.f));
    o.w = f2us(fmaxf(acc1[3] + bb.w, 0.f));
    *(ushort4*)((unsigned short*)fout + (size_t)row * 64 + c * 4) = o;
  }
}

// KNN accumulate: for point i, feature j (lane):
//   out[i*320 + j]      = WEXP*mean_k f[nk][j] - f[i][j]
//   out[i*320 + 64 + j] = WEXP*max_k  f[nk][j] - f[i][j]
// out is fp32, already offset by the output column base; row stride 320.
// One wave per point; 4 waves/block. idx is int32.
__global__ __launch_bounds__(256) void accum_kernel(
    const bf16* __restrict__ f,     // [n][64] bf16
    const int* __restrict__ idx,    // [n][32] int32
    float* __restrict__ out,        // fp32, row stride 320
    int n)
{
  const int wid = threadIdx.x >> 6;
  const int lane = threadIdx.x & 63;
  const int i = blockIdx.x * 4 + wid;
  if (i >= n) return;

  int iv = 0;
  if (lane < 32) iv = idx[(size_t)i * 32 + lane];

  const float self = us2f(((const unsigned short*)f)[(size_t)i * 64 + lane]);

  float sum = 0.f, mx = -3.4e38f;
#pragma unroll
  for (int k = 0; k < 32; ++k) {
    int nk = __shfl(iv, k);
    float v = us2f(((const unsigned short*)f)[(size_t)nk * 64 + lane]);
    sum += v;
    mx = fmaxf(mx, v);
  }

  const float meanv = sum * (WEXP / 32.0f);
  const float maxv = mx * WEXP;
  float* o = out + (size_t)i * 320 + lane;
  o[0] = meanv - self;
  o[64] = maxv - self;
}

extern "C" void kernel_launch(void* const* d_in, const int* in_sizes, int n_in,
                              void* d_out, int out_size, void* d_ws, size_t ws_size,
                              hipStream_t stream) {
  const float* x  = (const float*)d_in[0];
  const int* idx  = (const int*)d_in[1];   // int64 in reference, narrowed to int32 on device
  const float* W0 = (const float*)d_in[2];
  const float* b0 = (const float*)d_in[3];
  const float* W1 = (const float*)d_in[4];
  const float* b1 = (const float*)d_in[5];
  float* out = (float*)d_out;              // fp32 [n][320]
  const int n = in_sizes[0] / 64;

  bf16* fbuf = (bf16*)d_ws;  // [n][64] bf16, reused for f0 then f1 (25.6 MB)

  const int dblocks = (n + 31) / 32;
  const int ablocks = (n + 3) / 4;

  // layer 0: f0 = relu(x@W0+b0); also copy x (fp32) into out cols 256..319
  dense_relu_kernel<64><<<dblocks, 256, 0, stream>>>(x, 64, W0, b0, fbuf, out + 256, n);
  // accumulate -> out cols 0..127 (fp32)
  accum_kernel<<<ablocks, 256, 0, stream>>>(fbuf, idx, out, n);
  // layer 1: f1 = relu(out0@W1+b1), reading out cols 0..127 (fp32, stride 320)
  dense_relu_kernel<128><<<dblocks, 256, 0, stream>>>(out, 320, W1, b1, fbuf, nullptr, n);
  // accumulate -> out cols 128..255 (fp32)
  accum_kernel<<<ablocks, 256, 0, stream>>>(fbuf, idx, out + 128, n);
}